// Round 1
// 311.586 us; speedup vs baseline: 1.1223x; 1.1223x over previous
//
#include <hip/hip_runtime.h>
#include <math.h>

#define NB 64
#define NT 512
#define ND 768
#define NK 29
#define L2E 1.4426950408889634f
#define LN2 0.6931471805599453f
#define NEG_BIG -1e30f

typedef __attribute__((ext_vector_type(8))) short short8;
typedef __attribute__((ext_vector_type(4))) float floatx4;
typedef __attribute__((ext_vector_type(2))) unsigned u32x2;

__device__ __forceinline__ short bf16r(float f) {   // round-to-nearest-even
    unsigned u = __float_as_uint(f);
    unsigned r = (u + 0x7FFFu + ((u >> 16) & 1u)) >> 16;
    return (short)r;
}

// permlane32_swap(x,x): returns {lo-half-winner, hi-half-winner} broadcast to
// all 64 lanes, column-matched (each lane gets the values for ITS col = lane&31).
// Output order (which slot is lo vs hi) is resolved by the caller via the
// swapped indices, so we never depend on the builtin's slot convention.
__device__ __forceinline__ void swap32f(float x, float& a, float& b) {
    u32x2 r = __builtin_amdgcn_permlane32_swap(__float_as_uint(x),
                                               __float_as_uint(x), false, false);
    a = __uint_as_float(r[0]);
    b = __uint_as_float(r[1]);
}
__device__ __forceinline__ void swap32i(int x, int& a, int& b) {
    u32x2 r = __builtin_amdgcn_permlane32_swap((unsigned)x, (unsigned)x,
                                               false, false);
    a = (int)r[0];
    b = (int)r[1];
}

// ---------------------------------------------------------------------------
// Kernel 0: convert w (29x768 fp32) -> wbf (32x768 bf16, rows 29..31 zero)
// ---------------------------------------------------------------------------
__global__ __launch_bounds__(256) void k_prep(const float* __restrict__ w,
                                              short* __restrict__ wbf)
{
    int i = blockIdx.x * 256 + threadIdx.x;            // 32*768 = 24576
    if (i < 32 * ND) {
        int row = i / ND;
        wbf[i] = (row < NK) ? bf16r(w[i]) : (short)0;
    }
}

// ---------------------------------------------------------------------------
// Kernel 1: emissions via bf16 MFMA.  em[tok][k] = dot(emb[x[tok]], w[k]) + b[k]
// 2048 blocks x 128 thr (2 waves). Block = 16 tokens, N = 32 (cols 29..31 dead),
// K = 768 split across the 2 waves.
// MLP fix: the full A-panel (24 x float4 per lane) is loaded upfront into a
// flat register array -> 24 gather loads in flight per lane (vs ~6 with the
// old rolling prefetch). launch_bounds(128,3) keeps >=12 waves/CU resident.
// ---------------------------------------------------------------------------
__global__ __launch_bounds__(128, 3) void k_emissions(
    const int* __restrict__ x, const float* __restrict__ emb,
    const short* __restrict__ wbf, const float* __restrict__ bias,
    float* __restrict__ em)
{
    __shared__ float red[2 * 256];                     // wave1 partials
    const int lane = threadIdx.x & 63;
    const int wv = threadIdx.x >> 6;                   // d-half (0/1)
    const int col = lane & 15;                         // m for A, n for B
    const int quad = lane >> 4;                        // k-subrange selector
    const int Mbase = blockIdx.x * 16;
    const int tok = Mbase + col;

    const float* arow = emb + (size_t)x[tok] * ND + wv * 384 + quad * 8;
    const short* brow0 = wbf + (size_t)col * ND + wv * 384 + quad * 8;
    const short* brow1 = brow0 + 16 * ND;

    // issue ALL A loads first: 24 x global_load_dwordx4 in flight
    float4 a[24];
#pragma unroll
    for (int c = 0; c < 12; ++c) {
        a[2 * c]     = *(const float4*)(arow + c * 32);
        a[2 * c + 1] = *(const float4*)(arow + c * 32 + 4);
    }

    floatx4 acc0 = {0.f, 0.f, 0.f, 0.f};
    floatx4 acc1 = {0.f, 0.f, 0.f, 0.f};

    short8 b0 = *(const short8*)(brow0);               // B is L2-hot (45 KB)
    short8 b1 = *(const short8*)(brow1);

#pragma unroll
    for (int c = 0; c < 12; ++c) {
        int c1 = (c + 1 <= 11) ? c + 1 : 11;           // clamped prefetch
        short8 nb0 = *(const short8*)(brow0 + c1 * 32);
        short8 nb1 = *(const short8*)(brow1 + c1 * 32);

        short8 af;
        af[0] = bf16r(a[2 * c].x);     af[1] = bf16r(a[2 * c].y);
        af[2] = bf16r(a[2 * c].z);     af[3] = bf16r(a[2 * c].w);
        af[4] = bf16r(a[2 * c + 1].x); af[5] = bf16r(a[2 * c + 1].y);
        af[6] = bf16r(a[2 * c + 1].z); af[7] = bf16r(a[2 * c + 1].w);

        acc0 = __builtin_amdgcn_mfma_f32_16x16x32_bf16(af, b0, acc0, 0, 0, 0);
        acc1 = __builtin_amdgcn_mfma_f32_16x16x32_bf16(af, b1, acc1, 0, 0, 0);

        b0 = nb0; b1 = nb1;
    }

    // reduce the two d-halves; C/D layout: row = quad*4+reg, col = lane&15
    const int r0 = quad * 4;
    if (wv == 1) {
#pragma unroll
        for (int reg = 0; reg < 4; ++reg) {
            red[(r0 + reg) * 16 + col]       = acc0[reg];
            red[256 + (r0 + reg) * 16 + col] = acc1[reg];
        }
    }
    __syncthreads();
    if (wv == 0) {
        float bs0 = bias[col];
        float bs1 = (col < NK - 16) ? bias[16 + col] : 0.f;
#pragma unroll
        for (int reg = 0; reg < 4; ++reg) {
            int row = r0 + reg;
            float v0 = acc0[reg] + red[row * 16 + col] + bs0;
            em[(size_t)(Mbase + row) * NK + col] = v0;
            if (col < NK - 16) {
                float v1 = acc1[reg] + red[256 + row * 16 + col] + bs1;
                em[(size_t)(Mbase + row) * NK + 16 + col] = v1;
            }
        }
    }
}

// ---------------------------------------------------------------------------
// Kernel 2: scans. blocks 0..63 CRF forward, 64..127 Viterbi. 64 thr = 1 wave
// => barrier-free (in-order DS pipe within a wave).
// NEW split layout: col c = lane&31, half h = lane>>5 owns candidates
// [16h,16h+16). Per step: 4 broadcast ds_read_b128 + half-work, then one
// v_permlane32_swap (VALU pipe) combines the halves. Viterbi arithmetic is
// bitwise-identical to the reference (same candidate fp ops, exact first-max
// via adjacent-block tournament + id-ordered cross-half tie-break).
// ---------------------------------------------------------------------------
__global__ __launch_bounds__(64) void k_scan(
    const float* __restrict__ em, const int* __restrict__ tags,
    const float* __restrict__ st, const float* __restrict__ en,
    const float* __restrict__ tr, float* __restrict__ part,
    float* __restrict__ out)
{
    __shared__ __align__(16) float sA[32];
    __shared__ __align__(16) unsigned char smem[NT * NK * 4];
    const int lane = threadIdx.x;
    const int c = lane & 31;                            // column owned
    const int h = lane >> 5;                            // candidate half
    const int jc = (c < NK) ? c : NK - 1;
    const float4* sAh = (const float4*)(sA + 16 * h);   // this half's 16 states

    if (blockIdx.x < NB) {
        // ----------------- CRF forward (scaled exp domain) -----------------
        const int b = blockIdx.x;
        float* emS = (float*)smem;                     // [512][29]
        {
            const float4* src = (const float4*)(em + (size_t)b * NT * NK);
            float4* dst = (float4*)emS;
            for (int i = lane; i < NT * NK / 4; i += 64) dst[i] = src[i];
        }
        float ECh[16];
#pragma unroll
        for (int r = 0; r < 16; ++r) {
            int i = 16 * h + r;
            ECh[r] = (i < NK) ? __expf(tr[i * NK + jc]) : 0.f;
        }

        float a0v = __expf(st[jc] + emS[jc]);
        if (lane < 32) sA[lane] = (lane < NK) ? a0v : 0.f;

        int eshift = 5 * (NT - 1);
        float eemc = exp2f(fmaf(emS[NK + jc], L2E, -5.0f));
        float rawn = emS[2 * NK + jc];
        float anew = a0v;

        for (int t = 1; t < NT; ++t) {
            float4 A0 = sAh[0], A1 = sAh[1], A2 = sAh[2], A3 = sAh[3];
            float p0 = 0.f, p1 = 0.f, p2 = 0.f, p3 = 0.f;
            p0 = fmaf(A0.x, ECh[0], p0);  p1 = fmaf(A0.y, ECh[1], p1);
            p2 = fmaf(A0.z, ECh[2], p2);  p3 = fmaf(A0.w, ECh[3], p3);
            p0 = fmaf(A1.x, ECh[4], p0);  p1 = fmaf(A1.y, ECh[5], p1);
            p2 = fmaf(A1.z, ECh[6], p2);  p3 = fmaf(A1.w, ECh[7], p3);
            p0 = fmaf(A2.x, ECh[8], p0);  p1 = fmaf(A2.y, ECh[9], p1);
            p2 = fmaf(A2.z, ECh[10], p2); p3 = fmaf(A2.w, ECh[11], p3);
            p0 = fmaf(A3.x, ECh[12], p0); p1 = fmaf(A3.y, ECh[13], p1);
            p2 = fmaf(A3.z, ECh[14], p2); p3 = fmaf(A3.w, ECh[15], p3);
            float ph = (p0 + p1) + (p2 + p3);
            float plo, phi;
            swap32f(ph, plo, phi);                      // sum: order-agnostic
            anew = (plo + phi) * eemc;
            // refill (off critical chain)
            eemc = exp2f(fmaf(rawn, L2E, -5.0f));
            int tn = t + 2; tn = tn < NT ? tn : NT - 1;
            rawn = emS[tn * NK + jc];

            if ((t & 15) == 0) {       // exact pow2 renorm via lane-0 probe
                unsigned mb = (unsigned)__builtin_amdgcn_readfirstlane(
                                  __float_as_int(anew));
                int ex = (int)((mb >> 23) & 255u) - 127;
                anew *= __int_as_float((unsigned)(127 - ex) << 23);
                eshift += ex;
            }
            if (lane < 32) sA[lane] = (lane < NK) ? anew : 0.f;
        }
        float val = (lane < NK) ? anew * __expf(en[jc]) : 0.f;
#pragma unroll
        for (int s = 32; s; s >>= 1) val += __shfl_xor(val, s);
        float logZ = logf(val) + (float)eshift * LN2;
        const int* tg = tags + b * NT;
        float p = 0.f;
        for (int t = lane; t < NT; t += 64) {
            int tt = tg[t];
            p += emS[t * NK + tt];
            if (t == 0) p += st[tt];
            else        p += tr[tg[t - 1] * NK + tt];
            if (t == NT - 1) p += en[tt];
        }
#pragma unroll
        for (int s = 32; s; s >>= 1) p += __shfl_xor(p, s);
        if (lane == 0) part[b] = logZ - p;
    } else {
        // ----------------- Viterbi + parallel backtrace --------------------
        const int b = blockIdx.x - NB;
        const float* emb_b = em + (size_t)b * NT * NK;
        unsigned char* sbp = smem;                     // [511][32]
        unsigned char* smap = smem + 511 * 32;         // [16][32]

        float Tch[16];
        int idA[16];
#pragma unroll
        for (int r = 0; r < 16; ++r) {
            int i = 16 * h + r;
            Tch[r] = (i < NK) ? tr[i * NK + jc] : 0.f;
            idA[r] = i;
        }

        float sc = (c < NK) ? (st[jc] + emb_b[jc]) : NEG_BIG;
        if (lane < 32) sA[lane] = (c < NK) ? sc : NEG_BIG;

        float e0 = emb_b[1 * NK + jc];
        float e1 = emb_b[2 * NK + jc];
        float e2 = emb_b[3 * NK + jc];
        float e3 = emb_b[4 * NK + jc];

        auto vstep = [&](int t, float emt) {
            float4 q0 = sAh[0], q1 = sAh[1], q2 = sAh[2], q3 = sAh[3];
            float v[16];
            v[0]  = q0.x + Tch[0];  v[1]  = q0.y + Tch[1];
            v[2]  = q0.z + Tch[2];  v[3]  = q0.w + Tch[3];
            v[4]  = q1.x + Tch[4];  v[5]  = q1.y + Tch[5];
            v[6]  = q1.z + Tch[6];  v[7]  = q1.w + Tch[7];
            v[8]  = q2.x + Tch[8];  v[9]  = q2.y + Tch[9];
            v[10] = q2.z + Tch[10]; v[11] = q2.w + Tch[11];
            v[12] = q3.x + Tch[12]; v[13] = q3.y + Tch[13];
            v[14] = q3.z + Tch[14]; v[15] = q3.w + Tch[15];
            int id[16];
            // adjacent-block tournament: slots cover contiguous index ranges,
            // keep-left on tie => EXACT first-max within the half
#pragma unroll
            for (int i = 0; i < 16; i += 2) {
                bool g = v[i + 1] > v[i];
                v[i]  = g ? v[i + 1] : v[i];
                id[i] = g ? idA[i + 1] : idA[i];
            }
#pragma unroll
            for (int s = 2; s < 16; s <<= 1)
#pragma unroll
                for (int i = 0; i < 16; i += 2 * s) {
                    bool g = v[i + s] > v[i];
                    v[i]  = g ? v[i + s] : v[i];
                    id[i] = g ? id[i + s] : id[i];
                }
            // cross-half combine (id identifies which slot is lo/hi; ties ->
            // smaller id => global first-max, matching np.argmax)
            float va, vb; int ia, ib;
            swap32f(v[0], va, vb);
            swap32i(id[0], ia, ib);
            bool bb = (vb > va) || (vb == va && ib < ia);
            float bw = bb ? vb : va;
            int   bi = bb ? ib : ia;
            if (lane < 32) sbp[(t - 1) * 32 + lane] = (unsigned char)bi;
            sc = bw + emt;
            if (lane < 32) sA[lane] = (c < NK) ? sc : NEG_BIG;
        };

        int t = 1;
        for (; t + 3 < NT; t += 4) {
            vstep(t + 0, e0); { int tn = t + 4; tn = tn < NT ? tn : NT - 1; e0 = emb_b[tn * NK + jc]; }
            vstep(t + 1, e1); { int tn = t + 5; tn = tn < NT ? tn : NT - 1; e1 = emb_b[tn * NK + jc]; }
            vstep(t + 2, e2); { int tn = t + 6; tn = tn < NT ? tn : NT - 1; e2 = emb_b[tn * NK + jc]; }
            vstep(t + 3, e3); { int tn = t + 7; tn = tn < NT ? tn : NT - 1; e3 = emb_b[tn * NK + jc]; }
        }
        vstep(509, e0); vstep(510, e1); vstep(511, e2);

        float vfin = (lane < NK) ? (sc + en[jc]) : NEG_BIG;
        float M = vfin;
#pragma unroll
        for (int s = 32; s; s >>= 1) M = fmaxf(M, __shfl_xor(M, s));
        unsigned long long mk = __ballot((lane < NK) && vfin == M);
        int last = (int)__builtin_ctzll(mk);

        // parallel backtrace: 16 segment maps of 32 rows, 8 per lane-half
        int cur8[8];
#pragma unroll
        for (int rep = 0; rep < 8; ++rep) cur8[rep] = c;
        for (int off = 0; off < 32; ++off) {
#pragma unroll
            for (int rep = 0; rep < 8; ++rep) {
                int s = 2 * rep + h;
                int hi = (s == 15) ? 511 : 32 * s + 32;
                int r = hi - 1 - off;
                if (r >= 32 * s) cur8[rep] = sbp[r * 32 + cur8[rep]];
            }
        }
#pragma unroll
        for (int rep = 0; rep < 8; ++rep)
            smap[(2 * rep + h) * 32 + c] = (unsigned char)cur8[rep];

        int myhi = 0, cur = last;
        for (int s = 15; s >= 0; --s) {
            if (lane == s) myhi = cur;
            cur = smap[s * 32 + cur];
        }
        float* op = out + 1 + (size_t)b * NT;
        if (lane == 16) op[NT - 1] = (float)last;
        if (lane < 16) {
            int s = lane;
            int hi = (s == 15) ? 511 : 32 * s + 32;
            int cc = myhi;
            for (int r = hi - 1; r >= 32 * s; --r) {
                cc = sbp[r * 32 + cc];
                op[r] = (float)cc;
            }
        }
    }
}

// ---------------------------------------------------------------------------
// Kernel 3: nll = sum_b (logZ_b - num_b)
// ---------------------------------------------------------------------------
__global__ __launch_bounds__(64) void k_finish(const float* __restrict__ part,
                                               float* __restrict__ out)
{
    float v = part[threadIdx.x];
#pragma unroll
    for (int s = 32; s; s >>= 1) v += __shfl_xor(v, s);
    if (threadIdx.x == 0) out[0] = v;
}

extern "C" void kernel_launch(void* const* d_in, const int* in_sizes, int n_in,
                              void* d_out, int out_size, void* d_ws, size_t ws_size,
                              hipStream_t stream) {
    const int*   x    = (const int*)d_in[0];
    const int*   tags = (const int*)d_in[1];
    const float* emb  = (const float*)d_in[2];
    const float* w    = (const float*)d_in[3];
    const float* bias = (const float*)d_in[4];
    const float* st   = (const float*)d_in[5];
    const float* en   = (const float*)d_in[6];
    const float* tr   = (const float*)d_in[7];
    float* out = (float*)d_out;

    short* wbf  = (short*)d_ws;                              // 48 KB
    float* part = (float*)((char*)d_ws + 49152);             // 256 B
    float* em   = (float*)((char*)d_ws + 65536);             // 3.8 MB

    k_prep<<<96, 256, 0, stream>>>(w, wbf);
    k_emissions<<<2048, 128, 0, stream>>>(x, emb, wbf, bias, em);
    k_scan<<<2 * NB, 64, 0, stream>>>(em, tags, st, en, tr, part, out);
    k_finish<<<1, 64, 0, stream>>>(part, out);
}